// Round 5
// baseline (1938.816 us; speedup 1.0000x reference)
//
#include <hip/hip_runtime.h>

// Problem constants
#define BATCH 32
#define HIN 224
#define WIN 224
#define KCH 64
#define KS 7
#define OH 218
#define OW 218

// Tiling: 256 threads = 4 waves; each wave owns 8 consecutive output rows x full width.
// Block: 32 rows x 218 cols x 8 channels. 7 bands cover 218 rows (rows >=218 masked).
// Row parity is compile-time: h0 = band*32 (even), r0 = wave*8 (even) -> orow parity = i&1.
//   even i: lane L stores cols 4L..4L+3   (row byte off ≡ 0 mod 16 -> aligned float4)
//   odd  i: lane L stores cols 4L-2..4L+1 (row byte off ≡ 8 mod 16; (4L-2)*4 ≡ 8 -> aligned float4)
// All output store instructions are DENSE (no intra-instruction holes) and 16B-aligned.
// NO nontemporal: round-4 A/B showed nt adds ~1.1 GB of fabric RFO traffic on gfx950.
#define TILE_H 32
#define IN_TILE_H 38      // TILE_H + 6
#define LDS_STRIDE 240    // 4 leading zero-pad floats + 236 staged cols (16B-aligned rows)
#define CH_PER_BLOCK 8
#define NBANDS 7          // 7*32 = 224 >= 218

typedef float f32x4 __attribute__((ext_vector_type(4)));
typedef float f32x2 __attribute__((ext_vector_type(2)));

__device__ __forceinline__ void st4(float* p, float a, float b, float c, float d) {
    f32x4 v; v.x = a; v.y = b; v.z = c; v.w = d;
    *reinterpret_cast<f32x4*>(p) = v;
}
__device__ __forceinline__ void st2(float* p, float a, float b) {
    f32x2 v; v.x = a; v.y = b;
    *reinterpret_cast<f32x2*>(p) = v;
}

__global__ __launch_bounds__(256, 4)
void conv7x7_kernel(const float* __restrict__ x,
                    const float* __restrict__ kern,
                    float* __restrict__ out) {
    __shared__ float tile[IN_TILE_H][LDS_STRIDE];

    const int band = blockIdx.x;          // 0..6  (H bands of 32 rows)
    const int kg   = blockIdx.y;          // 0..7  (channel groups)
    const int b    = blockIdx.z;          // 0..31

    const int h0 = band * TILE_H;

    const int tid  = threadIdx.x;         // 0..255
    const int wv   = tid >> 6;            // wave 0..3
    const int lane = tid & 63;

    // ---- zero the 4-float leading pad (read by odd-row left-edge lanes) ----
    if (tid < IN_TILE_H) {
        f32x4 z; z.x = 0.f; z.y = 0.f; z.z = 0.f; z.w = 0.f;
        *reinterpret_cast<f32x4*>(&tile[tid][0]) = z;
    }

    // ---- stage input band: rows h0..h0+37, cols 0..235 at tile[r][4+col] ----
    const float* xb = x + b * (HIN * WIN);
    const int NV = (LDS_STRIDE - 4) / 4;  // 59 float4 per row
    for (int idx = tid; idx < IN_TILE_H * NV; idx += 256) {
        const int r  = idx / NV;
        const int cg = idx - r * NV;
        const int sr = h0 + r;
        const int sc = cg * 4;
        float4 v;
        if (sr < HIN && sc + 3 < WIN) {
            v = *reinterpret_cast<const float4*>(xb + sr * WIN + sc);
        } else {
            float t0 = (sr < HIN && sc + 0 < WIN) ? xb[sr * WIN + sc + 0] : 0.f;
            float t1 = (sr < HIN && sc + 1 < WIN) ? xb[sr * WIN + sc + 1] : 0.f;
            float t2 = (sr < HIN && sc + 2 < WIN) ? xb[sr * WIN + sc + 2] : 0.f;
            float t3 = (sr < HIN && sc + 3 < WIN) ? xb[sr * WIN + sc + 3] : 0.f;
            v = make_float4(t0, t1, t2, t3);
        }
        *reinterpret_cast<float4*>(&tile[r][4 + sc]) = v;
    }
    __syncthreads();

    const int r0 = wv * 8;                          // first out-row within band (even)
    const int cl = (lane < 54) ? lane : 54;         // clamp idle lanes (broadcast reads)
    const int c0 = cl * 4;                          // even-row first out-col

    #pragma unroll 1
    for (int kk = 0; kk < CH_PER_BLOCK; ++kk) {
        const int k = kg * CH_PER_BLOCK + kk;
        const float* __restrict__ wk = kern + k * (KS * KS);  // wave-uniform -> s_load

        float acc[8][4];
        #pragma unroll
        for (int i = 0; i < 8; ++i)
            #pragma unroll
            for (int j = 0; j < 4; ++j)
                acc[i][j] = 0.f;

        #pragma unroll
        for (int ii = 0; ii < 14; ++ii) {
            // xr covers tile float indices c0 .. c0+15 (input cols c0-4 .. c0+11)
            float xr[16];
            *reinterpret_cast<float4*>(&xr[0]) =
                *reinterpret_cast<const float4*>(&tile[r0 + ii][c0]);
            *reinterpret_cast<float4*>(&xr[4]) =
                *reinterpret_cast<const float4*>(&tile[r0 + ii][c0 + 4]);
            *reinterpret_cast<float4*>(&xr[8]) =
                *reinterpret_cast<const float4*>(&tile[r0 + ii][c0 + 8]);
            *reinterpret_cast<float4*>(&xr[12]) =
                *reinterpret_cast<const float4*>(&tile[r0 + ii][c0 + 12]);

            #pragma unroll
            for (int i = 0; i < 8; ++i) {
                const int ki = ii - i;
                if (ki >= 0 && ki < 7) {
                    const int ofs = (i & 1) ? 2 : 4;   // compile-time per i
                    #pragma unroll
                    for (int kj = 0; kj < 7; ++kj) {
                        const float wv2 = wk[ki * 7 + kj];
                        #pragma unroll
                        for (int j = 0; j < 4; ++j)
                            acc[i][j] = fmaf(wv2, xr[ofs + kj + j], acc[i][j]);
                    }
                }
            }
        }

        // ---- store: every instruction dense + 16B-aligned, write-allocate (no nt) ----
        float* ob = out + (size_t)(b * KCH + k) * (OH * OW);
        #pragma unroll
        for (int i = 0; i < 8; ++i) {
            const int orow = h0 + r0 + i;
            if (orow < OH) {
                float* rowp = ob + orow * OW;
                if ((i & 1) == 0) {
                    // even row: lanes 0..53 cover cols 0..215; lane 54 tail cols 216,217
                    if (lane < 54) {
                        st4(rowp + c0, acc[i][0], acc[i][1], acc[i][2], acc[i][3]);
                    } else if (lane == 54) {
                        st2(rowp + 216, acc[i][0], acc[i][1]);
                    }
                } else {
                    // odd row: lane L computed cols 4L-2..4L+1; lanes 1..54 cover 2..217;
                    // lane 0 head cols 0,1 (its acc[2],acc[3])
                    if (lane == 0) {
                        st2(rowp, acc[i][2], acc[i][3]);
                    } else if (lane <= 54) {
                        st4(rowp + c0 - 2, acc[i][0], acc[i][1], acc[i][2], acc[i][3]);
                    }
                }
            }
        }
    }
}

extern "C" void kernel_launch(void* const* d_in, const int* in_sizes, int n_in,
                              void* d_out, int out_size, void* d_ws, size_t ws_size,
                              hipStream_t stream) {
    const float* x    = (const float*)d_in[0];   // (32,224,224) f32
    const float* kern = (const float*)d_in[1];   // (64,7,7) f32
    float* out        = (float*)d_out;           // (32,64,218,218) f32

    dim3 grid(NBANDS, KCH / CH_PER_BLOCK, BATCH); // 7 x 8 x 32 = 1792 blocks
    dim3 block(256, 1, 1);
    conv7x7_kernel<<<grid, block, 0, stream>>>(x, kern, out);
}

// Round 8
// 1522.638 us; speedup vs baseline: 1.2733x; 1.2733x over previous
//
#include <hip/hip_runtime.h>

// Problem constants
#define BATCH 32
#define HIN 224
#define WIN 224
#define KCH 64
#define KS 7
#define OH 218
#define OW 218

// Tiling: 256 threads = 4 waves; each wave owns 8 consecutive output rows x full width.
// Block: 32 rows x 218 cols x 8 channels. 7 bands cover 218 rows (rows >=218 masked).
// Row parity compile-time: h0, r0 even -> orow parity = i&1.
//   even i: lane L stores cols 4L..4L+3   (16B-aligned float4)
//   odd  i: lane L stores cols 4L-2..4L+1 (row byte off ≡ 8 mod 16 -> also 16B-aligned)
// COMPUTE REWRITE (round 6): one output row at a time, window held in NAMED f32x4
// registers loaded straight from LDS. No float[] locals, no reinterpret-through-array:
// rounds 0-5's FETCH (2.6-3.9 GB) tracked per-thread window traffic exactly (1.42x
// read-count ratio -> 1.42x FETCH), implicating a scratch-resident window array.
#define TILE_H 32
#define IN_TILE_H 38      // TILE_H + 6
#define LDS_STRIDE 240    // 4 leading zero-pad floats + 236 staged cols
#define CH_PER_BLOCK 8
#define NBANDS 7          // 7*32 = 224 >= 218

typedef float f32x4 __attribute__((ext_vector_type(4)));
typedef float f32x2 __attribute__((ext_vector_type(2)));

__device__ __forceinline__ void st4(float* p, f32x4 v) {
    *reinterpret_cast<f32x4*>(p) = v;
}
__device__ __forceinline__ void st2(float* p, float a, float b) {
    f32x2 v; v.x = a; v.y = b;
    *reinterpret_cast<f32x2*>(p) = v;
}

__global__ __launch_bounds__(256, 4)
void conv7x7_kernel(const float* __restrict__ x,
                    const float* __restrict__ kern,
                    float* __restrict__ out) {
    __shared__ float tile[IN_TILE_H][LDS_STRIDE];

    const int band = blockIdx.x;          // 0..6  (H bands of 32 rows)
    const int kg   = blockIdx.y;          // 0..7  (channel groups)
    const int b    = blockIdx.z;          // 0..31

    const int h0 = band * TILE_H;

    const int tid  = threadIdx.x;         // 0..255
    const int wv   = tid >> 6;            // wave 0..3
    const int lane = tid & 63;

    // ---- zero the 4-float leading pad (read by odd-row left-edge lanes) ----
    if (tid < IN_TILE_H) {
        f32x4 z = {0.f, 0.f, 0.f, 0.f};
        *reinterpret_cast<f32x4*>(&tile[tid][0]) = z;
    }

    // ---- stage input band: rows h0..h0+37, cols 0..235 at tile[r][4+col] ----
    const float* xb = x + b * (HIN * WIN);
    const int NV = (LDS_STRIDE - 4) / 4;  // 59 float4 per row
    for (int idx = tid; idx < IN_TILE_H * NV; idx += 256) {
        const int r  = idx / NV;
        const int cg = idx - r * NV;
        const int sr = h0 + r;
        const int sc = cg * 4;
        float4 v;
        if (sr < HIN && sc + 3 < WIN) {
            v = *reinterpret_cast<const float4*>(xb + sr * WIN + sc);
        } else {
            float t0 = (sr < HIN && sc + 0 < WIN) ? xb[sr * WIN + sc + 0] : 0.f;
            float t1 = (sr < HIN && sc + 1 < WIN) ? xb[sr * WIN + sc + 1] : 0.f;
            float t2 = (sr < HIN && sc + 2 < WIN) ? xb[sr * WIN + sc + 2] : 0.f;
            float t3 = (sr < HIN && sc + 3 < WIN) ? xb[sr * WIN + sc + 3] : 0.f;
            v = make_float4(t0, t1, t2, t3);
        }
        *reinterpret_cast<float4*>(&tile[r][4 + sc]) = v;
    }
    __syncthreads();

    const int r0 = wv * 8;                          // first out-row within band (even)
    const int cl = (lane < 54) ? lane : 54;         // clamp idle lanes (broadcast reads)
    const int c0 = cl * 4;

    #pragma unroll 1
    for (int kk = 0; kk < CH_PER_BLOCK; ++kk) {
        const int k = kg * CH_PER_BLOCK + kk;
        const float* __restrict__ wk = kern + k * (KS * KS);  // wave-uniform -> s_load
        float* ob = out + (size_t)(b * KCH + k) * (OH * OW);

        #pragma unroll
        for (int i = 0; i < 8; ++i) {
            // even i: taps at tile[r][c0+4 + (kj+j)],  kj+j in 0..9
            // odd  i: taps at tile[r][c0   + (2+kj+j)], 2+kj+j in 2..11
            const int base = (i & 1) ? c0 : c0 + 4;   // folds per unrolled i
            const int sh   = (i & 1) ? 2 : 0;

            f32x4 acc = {0.f, 0.f, 0.f, 0.f};

            #pragma unroll
            for (int ki = 0; ki < 7; ++ki) {
                const float* rp = &tile[r0 + i + ki][0];
                const f32x4 w0 = *reinterpret_cast<const f32x4*>(rp + base);
                const f32x4 w1 = *reinterpret_cast<const f32x4*>(rp + base + 4);
                const f32x4 w2 = *reinterpret_cast<const f32x4*>(rp + base + 8);

                #pragma unroll
                for (int kj = 0; kj < 7; ++kj) {
                    const float wgt = wk[ki * 7 + kj];
                    #pragma unroll
                    for (int j = 0; j < 4; ++j) {
                        const int n = sh + kj + j;    // constant after unroll: 0..11
                        const float xv = (n < 4) ? w0[n]
                                       : (n < 8) ? w1[n - 4]
                                                 : w2[n - 8];
                        acc[j] = fmaf(wgt, xv, acc[j]);
                    }
                }
            }

            // ---- store row i: dense + 16B-aligned ----
            const int orow = h0 + r0 + i;
            if (orow < OH) {
                float* rowp = ob + orow * OW;
                if ((i & 1) == 0) {
                    // lanes 0..53 cover cols 0..215; lane 54 tail cols 216,217
                    if (lane < 54) {
                        st4(rowp + c0, acc);
                    } else if (lane == 54) {
                        st2(rowp + 216, acc[0], acc[1]);
                    }
                } else {
                    // lane L covers cols 4L-2..4L+1; lane 0 head cols 0,1
                    if (lane == 0) {
                        st2(rowp, acc[2], acc[3]);
                    } else if (lane <= 54) {
                        st4(rowp + c0 - 2, acc);
                    }
                }
            }
        }
    }
}

extern "C" void kernel_launch(void* const* d_in, const int* in_sizes, int n_in,
                              void* d_out, int out_size, void* d_ws, size_t ws_size,
                              hipStream_t stream) {
    const float* x    = (const float*)d_in[0];   // (32,224,224) f32
    const float* kern = (const float*)d_in[1];   // (64,7,7) f32
    float* out        = (float*)d_out;           // (32,64,218,218) f32

    dim3 grid(NBANDS, KCH / CH_PER_BLOCK, BATCH); // 7 x 8 x 32 = 1792 blocks
    dim3 block(256, 1, 1);
    conv7x7_kernel<<<grid, block, 0, stream>>>(x, kern, out);
}

// Round 12
// 580.552 us; speedup vs baseline: 3.3396x; 2.6227x over previous
//
#include <hip/hip_runtime.h>

// Problem constants
#define BATCH 32
#define HIN 224
#define WIN 224
#define KCH 64
#define KS 7
#define OH 218
#define OW 218

// Round 9: LDS-staged ALIGNED writeback.
// Surviving evidence: WRITE ~2x output and FETCH ~8x output across ALL store
// vectorization variants. Model: output rows (872 B) start misaligned to 64B
// (872 mod 64 = 40), so misaligned dense wave-stores put TWO partial-coverage
// 64B requests on every line -> RMW read+write per request at the memory side
// (write 2x observed ✓). Fix granularity = the 64B REQUEST, not the 16B store:
// stage each channel's 32x218 tile flat in LDS (region is 27,904 B, 64B-divisible
// per band), then copy out linearly with the thread->address map phase-shifted by
// the plane base misalignment (m = base&15 floats) so every quad-lane group emits
// a fully-covered aligned 64B line. <=2 partial requests per channel-tile.
#define TILE_H 32
#define IN_TILE_H 38      // TILE_H + 6
#define LDS_STRIDE 240    // 4 leading zero-pad floats + 236 staged cols
#define CH_PER_BLOCK 8
#define NBANDS 7          // 7*32 = 224 >= 218
#define OUT_TILE_F (TILE_H * OW)   // 6976 floats = 27,904 B

typedef float f32x4 __attribute__((ext_vector_type(4)));

__global__ __launch_bounds__(256, 2)
void conv7x7_kernel(const float* __restrict__ x,
                    const float* __restrict__ kern,
                    float* __restrict__ out) {
    __shared__ float tile[IN_TILE_H][LDS_STRIDE];   // 36,480 B
    __shared__ float otile[OUT_TILE_F];             // 27,904 B  (total 64,384 B)

    const int band = blockIdx.x;          // 0..6
    const int kg   = blockIdx.y;          // 0..7
    const int b    = blockIdx.z;          // 0..31

    const int h0 = band * TILE_H;

    const int tid  = threadIdx.x;         // 0..255
    const int wv   = tid >> 6;            // wave 0..3
    const int lane = tid & 63;

    // ---- zero the 4-float leading pad (read by odd-row left-edge lanes) ----
    if (tid < IN_TILE_H) {
        f32x4 z = {0.f, 0.f, 0.f, 0.f};
        *reinterpret_cast<f32x4*>(&tile[tid][0]) = z;
    }

    // ---- stage input band: rows h0..h0+37, cols 0..235 at tile[r][4+col] ----
    const float* xb = x + b * (HIN * WIN);
    const int NV = (LDS_STRIDE - 4) / 4;  // 59 float4 per row
    for (int idx = tid; idx < IN_TILE_H * NV; idx += 256) {
        const int r  = idx / NV;
        const int cg = idx - r * NV;
        const int sr = h0 + r;
        const int sc = cg * 4;
        float4 v;
        if (sr < HIN && sc + 3 < WIN) {
            v = *reinterpret_cast<const float4*>(xb + sr * WIN + sc);
        } else {
            float t0 = (sr < HIN && sc + 0 < WIN) ? xb[sr * WIN + sc + 0] : 0.f;
            float t1 = (sr < HIN && sc + 1 < WIN) ? xb[sr * WIN + sc + 1] : 0.f;
            float t2 = (sr < HIN && sc + 2 < WIN) ? xb[sr * WIN + sc + 2] : 0.f;
            float t3 = (sr < HIN && sc + 3 < WIN) ? xb[sr * WIN + sc + 3] : 0.f;
            v = make_float4(t0, t1, t2, t3);
        }
        *reinterpret_cast<float4*>(&tile[r][4 + sc]) = v;
    }
    __syncthreads();

    const int r0 = wv * 8;                          // first out-row within band (even)
    const int cl = (lane < 54) ? lane : 54;         // clamp idle lanes (broadcast reads)
    const int c0 = cl * 4;

    #pragma unroll 1
    for (int kk = 0; kk < CH_PER_BLOCK; ++kk) {
        const int k = kg * CH_PER_BLOCK + kk;
        const float* __restrict__ wk = kern + k * (KS * KS);  // wave-uniform -> s_load

        // ---- compute 8 rows, write each into the flat LDS output tile ----
        #pragma unroll
        for (int i = 0; i < 8; ++i) {
            // even i: taps at tile[r][c0+4 + (kj+j)];  odd i: shifted -2 (cols 4L-2..4L+1)
            const int base = (i & 1) ? c0 : c0 + 4;
            const int sh   = (i & 1) ? 2 : 0;

            f32x4 acc = {0.f, 0.f, 0.f, 0.f};

            #pragma unroll
            for (int ki = 0; ki < 7; ++ki) {
                const float* rp = &tile[r0 + i + ki][0];
                const f32x4 w0 = *reinterpret_cast<const f32x4*>(rp + base);
                const f32x4 w1 = *reinterpret_cast<const f32x4*>(rp + base + 4);
                const f32x4 w2 = *reinterpret_cast<const f32x4*>(rp + base + 8);

                #pragma unroll
                for (int kj = 0; kj < 7; ++kj) {
                    const float wgt = wk[ki * 7 + kj];
                    #pragma unroll
                    for (int j = 0; j < 4; ++j) {
                        const int n = sh + kj + j;    // constant after unroll: 0..11
                        const float xv = (n < 4) ? w0[n]
                                       : (n < 8) ? w1[n - 4]
                                                 : w2[n - 8];
                        acc[j] = fmaf(wgt, xv, acc[j]);
                    }
                }
            }

            // write row i into otile (flat 32x218 image; rows beyond OH land in
            // unused buffer space and are skipped by the copy)
            const int ot = (r0 + i) * OW;
            if ((i & 1) == 0) {
                if (lane < 54) {
                    *reinterpret_cast<f32x4*>(&otile[ot + c0]) = acc;  // 16B-aligned
                } else if (lane == 54) {
                    otile[ot + 216] = acc[0];
                    otile[ot + 217] = acc[1];
                }
            } else {
                if (lane == 0) {
                    otile[ot]     = acc[2];
                    otile[ot + 1] = acc[3];
                } else if (lane <= 54) {
                    *reinterpret_cast<f32x4*>(&otile[ot + c0 - 2]) = acc;  // 16B-aligned
                }
            }
        }
        __syncthreads();   // otile complete

        // ---- aligned linear copy-out: quad-lane groups emit full 64B lines ----
        const size_t A0 = (size_t)(b * KCH + k) * (OH * OW) + (size_t)h0 * OW;
        const int   m   = (int)(A0 & 15);            // phase shift (floats, multiple of 4)
        float* gbase = out + A0;
        const int Lr = ((h0 + TILE_H <= OH) ? TILE_H : (OH - h0)) * OW;  // valid floats

        #pragma unroll 1
        for (int g = tid * 4 - m; g < Lr; g += 1024) {
            if (g >= 0 && g + 4 <= Lr) {
                *reinterpret_cast<f32x4*>(gbase + g) =
                    *reinterpret_cast<const f32x4*>(&otile[g]);
            } else {
                #pragma unroll
                for (int u = 0; u < 4; ++u) {
                    const int gu = g + u;
                    if (gu >= 0 && gu < Lr) gbase[gu] = otile[gu];
                }
            }
        }
        __syncthreads();   // copy done before next channel overwrites otile
    }
}

extern "C" void kernel_launch(void* const* d_in, const int* in_sizes, int n_in,
                              void* d_out, int out_size, void* d_ws, size_t ws_size,
                              hipStream_t stream) {
    const float* x    = (const float*)d_in[0];   // (32,224,224) f32
    const float* kern = (const float*)d_in[1];   // (64,7,7) f32
    float* out        = (float*)d_out;           // (32,64,218,218) f32

    dim3 grid(NBANDS, KCH / CH_PER_BLOCK, BATCH); // 7 x 8 x 32 = 1792 blocks
    dim3 block(256, 1, 1);
    conv7x7_kernel<<<grid, block, 0, stream>>>(x, kern, out);
}

// Round 17
// 542.848 us; speedup vs baseline: 3.5716x; 1.0695x over previous
//
#include <hip/hip_runtime.h>

// Problem constants
#define BATCH 32
#define HIN 224
#define WIN 224
#define KCH 64
#define KS 7
#define OH 218
#define OW 218

// Round 13: input-row-major accumulation on top of round-12's aligned writeback.
// r12 confirmed the 64B-request RMW model (FETCH 3.37GB -> 26MB, WRITE 2x -> 1x,
// 1350 -> 290us). New bottleneck arithmetic: per-output-row compute reads
// 168 b128/thread/channel from LDS (~186us at m134's 85 B/cyc/CU) vs VALU floor
// ~73us. This round: iterate the 14 INPUT rows, load each lane window once
// (4 b128), update all 8 row accumulators -> 56 b128/thread/channel (3x less).
// acc[8] is f32x4 with ALL indices compile-time (full unroll) - no scratch risk.
// Staging, otile writes, aligned copy-out byte-identical to r12.
#define TILE_H 32
#define IN_TILE_H 38      // TILE_H + 6
#define LDS_STRIDE 240    // 4 leading zero-pad floats + 236 staged cols
#define CH_PER_BLOCK 8
#define NBANDS 7          // 7*32 = 224 >= 218
#define OUT_TILE_F (TILE_H * OW)   // 6976 floats = 27,904 B

typedef float f32x4 __attribute__((ext_vector_type(4)));

__global__ __launch_bounds__(256, 2)
void conv7x7_kernel(const float* __restrict__ x,
                    const float* __restrict__ kern,
                    float* __restrict__ out) {
    __shared__ float tile[IN_TILE_H][LDS_STRIDE];   // 36,480 B
    __shared__ float otile[OUT_TILE_F];             // 27,904 B  (total 64,384 B)

    const int band = blockIdx.x;          // 0..6
    const int kg   = blockIdx.y;          // 0..7
    const int b    = blockIdx.z;          // 0..31

    const int h0 = band * TILE_H;

    const int tid  = threadIdx.x;         // 0..255
    const int wv   = tid >> 6;            // wave 0..3
    const int lane = tid & 63;

    // ---- zero the 4-float leading pad (read by odd-row left-edge lanes) ----
    if (tid < IN_TILE_H) {
        f32x4 z = {0.f, 0.f, 0.f, 0.f};
        *reinterpret_cast<f32x4*>(&tile[tid][0]) = z;
    }

    // ---- stage input band: rows h0..h0+37, cols 0..235 at tile[r][4+col] ----
    const float* xb = x + b * (HIN * WIN);
    const int NV = (LDS_STRIDE - 4) / 4;  // 59 float4 per row
    for (int idx = tid; idx < IN_TILE_H * NV; idx += 256) {
        const int r  = idx / NV;
        const int cg = idx - r * NV;
        const int sr = h0 + r;
        const int sc = cg * 4;
        float4 v;
        if (sr < HIN && sc + 3 < WIN) {
            v = *reinterpret_cast<const float4*>(xb + sr * WIN + sc);
        } else {
            float t0 = (sr < HIN && sc + 0 < WIN) ? xb[sr * WIN + sc + 0] : 0.f;
            float t1 = (sr < HIN && sc + 1 < WIN) ? xb[sr * WIN + sc + 1] : 0.f;
            float t2 = (sr < HIN && sc + 2 < WIN) ? xb[sr * WIN + sc + 2] : 0.f;
            float t3 = (sr < HIN && sc + 3 < WIN) ? xb[sr * WIN + sc + 3] : 0.f;
            v = make_float4(t0, t1, t2, t3);
        }
        *reinterpret_cast<float4*>(&tile[r][4 + sc]) = v;
    }
    __syncthreads();

    const int r0 = wv * 8;                          // first out-row within band (even)
    const int cl = (lane < 54) ? lane : 54;         // clamp idle lanes (broadcast reads)
    const int c0 = cl * 4;

    #pragma unroll 1
    for (int kk = 0; kk < CH_PER_BLOCK; ++kk) {
        const int k = kg * CH_PER_BLOCK + kk;
        const float* __restrict__ wk = kern + k * (KS * KS);  // wave-uniform -> s_load

        f32x4 acc[8];
        #pragma unroll
        for (int i = 0; i < 8; ++i) {
            f32x4 z = {0.f, 0.f, 0.f, 0.f};
            acc[i] = z;
        }

        // ---- input-row-major: load window once, feed all live output rows ----
        #pragma unroll
        for (int ii = 0; ii < 14; ++ii) {
            const float* rp = &tile[r0 + ii][0];
            const f32x4 w0 = *reinterpret_cast<const f32x4*>(rp + c0);
            const f32x4 w1 = *reinterpret_cast<const f32x4*>(rp + c0 + 4);
            const f32x4 w2 = *reinterpret_cast<const f32x4*>(rp + c0 + 8);
            const f32x4 w3 = *reinterpret_cast<const f32x4*>(rp + c0 + 12);

            #pragma unroll
            for (int i = 0; i < 8; ++i) {
                const int ki = ii - i;                 // folds per (ii,i)
                if (ki >= 0 && ki < 7) {
                    const int sh = (i & 1) ? 2 : 4;    // odd rows shifted -2
                    #pragma unroll
                    for (int kj = 0; kj < 7; ++kj) {
                        const float wgt = wk[ki * 7 + kj];
                        #pragma unroll
                        for (int j = 0; j < 4; ++j) {
                            const int n = sh + kj + j;   // constant: 2..13
                            const float xv = (n < 4)  ? w0[n]
                                           : (n < 8)  ? w1[n - 4]
                                           : (n < 12) ? w2[n - 8]
                                                      : w3[n - 12];
                            acc[i][j] = fmaf(wgt, xv, acc[i][j]);
                        }
                    }
                }
            }
        }

        // ---- write rows into flat LDS output tile (identical to r12) ----
        #pragma unroll
        for (int i = 0; i < 8; ++i) {
            const int ot = (r0 + i) * OW;
            if ((i & 1) == 0) {
                if (lane < 54) {
                    *reinterpret_cast<f32x4*>(&otile[ot + c0]) = acc[i];
                } else if (lane == 54) {
                    otile[ot + 216] = acc[i][0];
                    otile[ot + 217] = acc[i][1];
                }
            } else {
                if (lane == 0) {
                    otile[ot]     = acc[i][2];
                    otile[ot + 1] = acc[i][3];
                } else if (lane <= 54) {
                    *reinterpret_cast<f32x4*>(&otile[ot + c0 - 2]) = acc[i];
                }
            }
        }
        __syncthreads();   // otile complete

        // ---- aligned linear copy-out: quad-lane groups emit full 64B lines ----
        const size_t A0 = (size_t)(b * KCH + k) * (OH * OW) + (size_t)h0 * OW;
        const int   m   = (int)(A0 & 15);            // phase shift (floats, multiple of 4)
        float* gbase = out + A0;
        const int Lr = ((h0 + TILE_H <= OH) ? TILE_H : (OH - h0)) * OW;  // valid floats

        #pragma unroll 1
        for (int g = tid * 4 - m; g < Lr; g += 1024) {
            if (g >= 0 && g + 4 <= Lr) {
                *reinterpret_cast<f32x4*>(gbase + g) =
                    *reinterpret_cast<const f32x4*>(&otile[g]);
            } else {
                #pragma unroll
                for (int u = 0; u < 4; ++u) {
                    const int gu = g + u;
                    if (gu >= 0 && gu < Lr) gbase[gu] = otile[gu];
                }
            }
        }
        __syncthreads();   // copy done before next channel overwrites otile
    }
}

extern "C" void kernel_launch(void* const* d_in, const int* in_sizes, int n_in,
                              void* d_out, int out_size, void* d_ws, size_t ws_size,
                              hipStream_t stream) {
    const float* x    = (const float*)d_in[0];   // (32,224,224) f32
    const float* kern = (const float*)d_in[1];   // (64,7,7) f32
    float* out        = (float*)d_out;           // (32,64,218,218) f32

    dim3 grid(NBANDS, KCH / CH_PER_BLOCK, BATCH); // 7 x 8 x 32 = 1792 blocks
    dim3 block(256, 1, 1);
    conv7x7_kernel<<<grid, block, 0, stream>>>(x, kern, out);
}